// Round 1
// baseline (1210.914 us; speedup 1.0000x reference)
//
#include <hip/hip_runtime.h>
#include <cstdint>
#include <cstddef>

#define BN_EPS 1e-5f

// ---------------- utility ----------------
__global__ void zero_i32_k(int* p, int n) {
  int i = blockIdx.x * blockDim.x + threadIdx.x;
  if (i < n) p[i] = 0;
}
__global__ void zero_f32_k(float* p, int n) {
  int i = blockIdx.x * blockDim.x + threadIdx.x;
  if (i < n) p[i] = 0.f;
}

// ---------------- CSR build over dst ----------------
__global__ void hist_k(const int* __restrict__ dst, int* __restrict__ cnt, int E) {
  int e = blockIdx.x * blockDim.x + threadIdx.x;
  if (e < E) atomicAdd(&cnt[dst[e]], 1);
}

// exclusive scan over N=4096 (single block, 1024 threads, 4 elems/thread)
__global__ __launch_bounds__(1024) void scan_k(const int* __restrict__ cnt,
                                               int* __restrict__ offsets,
                                               int* __restrict__ cursor,
                                               int N, int total) {
  __shared__ int part[1024];
  int t = threadIdx.x;
  int a0 = cnt[4*t+0], a1 = cnt[4*t+1], a2 = cnt[4*t+2], a3 = cnt[4*t+3];
  part[t] = a0 + a1 + a2 + a3;
  __syncthreads();
  for (int off = 1; off < 1024; off <<= 1) {
    int v = (t >= off) ? part[t - off] : 0;
    __syncthreads();
    part[t] += v;
    __syncthreads();
  }
  int excl = (t == 0) ? 0 : part[t-1];
  int o0 = excl, o1 = o0 + a0, o2 = o1 + a1, o3 = o2 + a2;
  offsets[4*t+0] = o0; offsets[4*t+1] = o1; offsets[4*t+2] = o2; offsets[4*t+3] = o3;
  cursor [4*t+0] = o0; cursor [4*t+1] = o1; cursor [4*t+2] = o2; cursor [4*t+3] = o3;
  if (t == 0) offsets[N] = total;
}

__global__ void scatter_k(const int* __restrict__ dst, int* __restrict__ cursor,
                          int* __restrict__ csr, int E) {
  int e = blockIdx.x * blockDim.x + threadIdx.x;
  if (e < E) {
    int d = dst[e];
    int pos = atomicAdd(&cursor[d], 1);
    csr[pos] = e;
  }
}

// ---------------- edge MLP first stage: z = [relu(ea@W1+b1), 1] ----------------
__global__ void edge_z_k(const float* __restrict__ ea, const float* __restrict__ W1,
                         const float* __restrict__ b1, float* __restrict__ z, int E) {
  int idx = blockIdx.x * blockDim.x + threadIdx.x;
  if (idx >= E * 33) return;
  int e = idx / 33;
  int k = idx - e * 33;
  float v;
  if (k == 32) {
    v = 1.f;  // constant channel carries the b2 term through S
  } else {
    float a0 = ea[e*3+0], a1 = ea[e*3+1], a2 = ea[e*3+2];
    v = fmaxf(a0 * W1[k] + a1 * W1[32 + k] + a2 * W1[64 + k] + b1[k], 0.f);
  }
  z[idx] = v;
}

// ---------------- W2' permute: [34*cin, cout]; rows 0..31 from W2, 32 = b2, 33 = root ----------------
__global__ void build_W2p_k(const float* __restrict__ W2, const float* __restrict__ b2,
                            const float* __restrict__ root, float* __restrict__ W2p,
                            int cin, int cout) {
  int idx = blockIdx.x * blockDim.x + threadIdx.x;
  int total = 34 * cin * cout;
  if (idx >= total) return;
  int o  = idx % cout;
  int ki = idx / cout;
  int k  = ki / cin;
  int i  = ki - k * cin;
  float v;
  if (k < 32)       v = W2[(size_t)k * cin * cout + (size_t)i * cout + o];
  else if (k == 32) v = b2[(size_t)i * cout + o];
  else              v = root[(size_t)i * cout + o];
  W2p[idx] = v;
}

// ---------------- S build: S[n, k*cin+i] = (1/deg) * sum_{e in dst==n} z[e,k]*h[src[e],i];
//                  rows [33*cin, 34*cin) = h[n,:] (unscaled, for the root term) ----------------
template<int CIN>
__global__ __launch_bounds__(256) void build_S_k(const float* __restrict__ h,
                                                 const float* __restrict__ z,
                                                 const int* __restrict__ src,
                                                 const int* __restrict__ csr,
                                                 const int* __restrict__ offsets,
                                                 float* __restrict__ S) {
  constexpr int CH = 8;
  constexpr int K1 = 33 * CIN;
  constexpr int KT = 34 * CIN;
  constexpr int NACC = (K1 + 255) / 256;
  __shared__ float hs[CH][CIN];
  __shared__ float zs[CH][33];
  __shared__ int   es[CH];
  const int n = blockIdx.x;
  const int tid = threadIdx.x;
  const int base = offsets[n];
  const int deg  = offsets[n+1] - base;
  const float scale = 1.f / fmaxf((float)deg, 1.f);
  float acc[NACC];
#pragma unroll
  for (int q = 0; q < NACC; q++) acc[q] = 0.f;

  for (int c0 = 0; c0 < deg; c0 += CH) {
    const int cc = min(CH, deg - c0);
    if (tid < cc) es[tid] = csr[base + c0 + tid];
    __syncthreads();
    for (int idx = tid; idx < cc * CIN; idx += 256) {
      int e_slot = idx / CIN, i = idx - e_slot * CIN;
      hs[e_slot][i] = h[(size_t)src[es[e_slot]] * CIN + i];
    }
    for (int idx = tid; idx < cc * 33; idx += 256) {
      int e_slot = idx / 33, k = idx - e_slot * 33;
      zs[e_slot][k] = z[(size_t)es[e_slot] * 33 + k];
    }
    __syncthreads();
#pragma unroll
    for (int q = 0; q < NACC; q++) {
      int ki = tid + q * 256;
      if (ki < K1) {
        int k = ki / CIN, i = ki - (ki / CIN) * CIN;
        float a = acc[q];
        for (int c = 0; c < cc; c++) a += zs[c][k] * hs[c][i];
        acc[q] = a;
      }
    }
    __syncthreads();
  }
#pragma unroll
  for (int q = 0; q < NACC; q++) {
    int ki = tid + q * 256;
    if (ki < K1) S[(size_t)n * KT + ki] = acc[q] * scale;
  }
  for (int i = tid; i < CIN; i += 256) S[(size_t)n * KT + K1 + i] = h[(size_t)n * CIN + i];
}

// ---------------- fp32 tiled GEMM with fused bias + BN + ReLU epilogue ----------------
// C[row,col] = relu( bn( A[row,:]@B[:,col] + bias[col] ) ), A: (4096,K), B: (K,Ncol)
__global__ __launch_bounds__(256) void gemm_k(const float* __restrict__ A,
                                              const float* __restrict__ B,
                                              const float* __restrict__ bias,
                                              const float* __restrict__ bg,
                                              const float* __restrict__ bb,
                                              const float* __restrict__ bnm,
                                              const float* __restrict__ bnv,
                                              float* __restrict__ C, int K, int Ncol) {
  constexpr int BM = 64, BN = 64, BK = 16;
  __shared__ __align__(16) float As[BK][BM + 4];
  __shared__ __align__(16) float Bs[BK][BN + 4];
  const int m0 = blockIdx.x * BM, n0 = blockIdx.y * BN;
  const int tid = threadIdx.x;
  const int tm = tid >> 4, tn = tid & 15;
  float acc[4][4];
#pragma unroll
  for (int p = 0; p < 4; p++)
#pragma unroll
    for (int q = 0; q < 4; q++) acc[p][q] = 0.f;

  for (int k0 = 0; k0 < K; k0 += BK) {
#pragma unroll
    for (int li = tid; li < BM * BK; li += 256) {
      int i = li >> 4, j = li & 15;
      int kk = k0 + j;
      As[j][i] = (kk < K) ? A[(size_t)(m0 + i) * K + kk] : 0.f;
    }
#pragma unroll
    for (int li = tid; li < BK * BN; li += 256) {
      int j = li >> 6, o = li & 63;
      int kk = k0 + j;
      Bs[j][o] = (kk < K) ? B[(size_t)kk * Ncol + n0 + o] : 0.f;
    }
    __syncthreads();
#pragma unroll
    for (int j = 0; j < BK; j++) {
      float4 a4 = *(const float4*)(&As[j][tm * 4]);
      float4 b4 = *(const float4*)(&Bs[j][tn * 4]);
      float a[4] = {a4.x, a4.y, a4.z, a4.w};
      float b[4] = {b4.x, b4.y, b4.z, b4.w};
#pragma unroll
      for (int p = 0; p < 4; p++)
#pragma unroll
        for (int q = 0; q < 4; q++) acc[p][q] += a[p] * b[q];
    }
    __syncthreads();
  }
#pragma unroll
  for (int p = 0; p < 4; p++) {
    int row = m0 + tm * 4 + p;
#pragma unroll
    for (int q = 0; q < 4; q++) {
      int col = n0 + tn * 4 + q;
      float val = acc[p][q] + bias[col];
      val = bg[col] * (val - bnm[col]) * rsqrtf(bnv[col] + BN_EPS) + bb[col];
      C[(size_t)row * Ncol + col] = fmaxf(val, 0.f);
    }
  }
}

// ---------------- pooling ----------------
__global__ void pool_k(const float* __restrict__ h, const int* __restrict__ seg,
                       float* __restrict__ psum, float* __restrict__ pcnt) {
  int n = blockIdx.x, o = threadIdx.x;  // 256 threads
  int g = seg[n];
  atomicAdd(&psum[(size_t)g * 256 + o], h[(size_t)n * 256 + o]);
  if (o == 0) atomicAdd(&pcnt[g], 1.f);
}

__global__ __launch_bounds__(128) void final_k(const float* __restrict__ psum,
                                               const float* __restrict__ pcnt,
                                               const float* __restrict__ W,
                                               const float* __restrict__ b,
                                               float* __restrict__ out, int T) {
  __shared__ float pooled[256];
  int g = blockIdx.x, t = threadIdx.x;
  float ic = 1.f / fmaxf(pcnt[g], 1.f);
  for (int o = t; o < 256; o += 128) pooled[o] = psum[(size_t)g * 256 + o] * ic;
  __syncthreads();
  if (t < T) {
    float s = b[t];
    for (int o = 0; o < 256; o++) s += pooled[o] * W[(size_t)o * T + t];
    out[(size_t)g * T + t] = (s > 0.f) ? s : 0.1f * s;
  }
}

// ---------------- host orchestration ----------------
extern "C" void kernel_launch(void* const* d_in, const int* in_sizes, int n_in,
                              void* d_out, int out_size, void* d_ws, size_t ws_size,
                              hipStream_t stream) {
  const float* x   = (const float*)d_in[0];
  const int*   ei  = (const int*)d_in[1];
  const float* ea  = (const float*)d_in[2];
  const int*   seg = (const int*)d_in[3];

  const int N = in_sizes[0] / 5;       // 4096
  const int E = in_sizes[2] / 3;       // 16384
  const int T = in_sizes[35];          // 100
  const int G = out_size / T;          // 128
  const int* src = ei;
  const int* dst = ei + E;

  const float *W1[3], *b1[3], *W2[3], *b2[3], *root[3], *bias[3];
  const float *bng[3], *bnb[3], *bnm[3], *bnv[3];
  for (int l = 0; l < 3; l++) {
    int base = 4 + l * 10;
    W1[l]   = (const float*)d_in[base + 0];
    b1[l]   = (const float*)d_in[base + 1];
    W2[l]   = (const float*)d_in[base + 2];
    b2[l]   = (const float*)d_in[base + 3];
    root[l] = (const float*)d_in[base + 4];
    bias[l] = (const float*)d_in[base + 5];
    bng[l]  = (const float*)d_in[base + 6];
    bnb[l]  = (const float*)d_in[base + 7];
    bnm[l]  = (const float*)d_in[base + 8];
    bnv[l]  = (const float*)d_in[base + 9];
  }
  const float* mlpW = (const float*)d_in[34];
  const float* mlpb = (const float*)d_in[35];

  // workspace carve (256B aligned chunks)
  char* p = (char*)d_ws;
  auto carve = [&](size_t bytes) -> char* {
    char* r = p;
    p += (bytes + 255) & ~(size_t)255;
    return r;
  };
  int*   cnt     = (int*)carve((size_t)N * 4);
  int*   offsets = (int*)carve((size_t)(N + 1) * 4);
  int*   cursor  = (int*)carve((size_t)N * 4);
  int*   csr     = (int*)carve((size_t)E * 4);
  float* z       = (float*)carve((size_t)E * 33 * 4);
  float* W2p     = (float*)carve((size_t)34 * 128 * 256 * 4);
  float* S       = (float*)carve((size_t)N * 34 * 128 * 4);
  float* hA      = (float*)carve((size_t)N * 256 * 4);
  float* hB      = (float*)carve((size_t)N * 256 * 4);
  float* psum    = (float*)carve((size_t)G * 256 * 4);
  float* pcnt    = (float*)carve((size_t)G * 4);

  // CSR over dst
  zero_i32_k<<<(N + 255) / 256, 256, 0, stream>>>(cnt, N);
  hist_k<<<(E + 255) / 256, 256, 0, stream>>>(dst, cnt, E);
  scan_k<<<1, 1024, 0, stream>>>(cnt, offsets, cursor, N, E);
  scatter_k<<<(E + 255) / 256, 256, 0, stream>>>(dst, cursor, csr, E);

  const int cins[3]  = {5, 64, 128};
  const int couts[3] = {64, 128, 256};
  const float* hin = x;
  float* houts[3] = {hA, hB, hA};

  for (int l = 0; l < 3; l++) {
    int cin = cins[l], cout = couts[l], K = 34 * cin;
    edge_z_k<<<(E * 33 + 255) / 256, 256, 0, stream>>>(ea, W1[l], b1[l], z, E);
    build_W2p_k<<<(K * cout + 255) / 256, 256, 0, stream>>>(W2[l], b2[l], root[l], W2p, cin, cout);
    if (cin == 5)
      build_S_k<5><<<N, 256, 0, stream>>>(hin, z, src, csr, offsets, S);
    else if (cin == 64)
      build_S_k<64><<<N, 256, 0, stream>>>(hin, z, src, csr, offsets, S);
    else
      build_S_k<128><<<N, 256, 0, stream>>>(hin, z, src, csr, offsets, S);
    dim3 grid(N / 64, cout / 64);
    gemm_k<<<grid, 256, 0, stream>>>(S, W2p, bias[l], bng[l], bnb[l], bnm[l], bnv[l],
                                     houts[l], K, cout);
    hin = houts[l];
  }

  zero_f32_k<<<(G * 256 + 255) / 256, 256, 0, stream>>>(psum, G * 256);
  zero_f32_k<<<(G + 255) / 256, 256, 0, stream>>>(pcnt, G);
  pool_k<<<N, 256, 0, stream>>>(hA, seg, psum, pcnt);
  final_k<<<G, 128, 0, stream>>>(psum, pcnt, mlpW, mlpb, (float*)d_out, T);
}

// Round 2
// 362.800 us; speedup vs baseline: 3.3377x; 3.3377x over previous
//
#include <hip/hip_runtime.h>
#include <cstdint>
#include <cstddef>

#define BN_EPS 1e-5f

typedef short bf16x8 __attribute__((ext_vector_type(8)));
typedef float f32x4  __attribute__((ext_vector_type(4)));

__device__ __forceinline__ uint16_t f2bf_rte(float f) {
  uint32_t u = __float_as_uint(f);
  uint32_t r = u + 0x7fffu + ((u >> 16) & 1u);
  return (uint16_t)(r >> 16);
}
__device__ __forceinline__ float bf2f(uint16_t h) {
  return __uint_as_float(((uint32_t)h) << 16);
}
__device__ __forceinline__ void split_bf(float v, uint16_t& hi, uint16_t& lo) {
  hi = f2bf_rte(v);
  lo = f2bf_rte(v - bf2f(hi));
}

// ---------------- utility ----------------
__global__ void zero_f32_k(float* p, int n) {
  int i = blockIdx.x * blockDim.x + threadIdx.x;
  if (i < n) p[i] = 0.f;
}
__global__ void zero_i32_k(int* p, int n) {
  int i = blockIdx.x * blockDim.x + threadIdx.x;
  if (i < n) p[i] = 0;
}

// ---------------- CSR build over dst ----------------
__global__ void hist_k(const int* __restrict__ dst, int* __restrict__ cnt, int E) {
  int e = blockIdx.x * blockDim.x + threadIdx.x;
  if (e < E) atomicAdd(&cnt[dst[e]], 1);
}

__global__ __launch_bounds__(1024) void scan_k(const int* __restrict__ cnt,
                                               int* __restrict__ offsets,
                                               int* __restrict__ cursor,
                                               int N, int total) {
  __shared__ int part[1024];
  int t = threadIdx.x;
  int a0 = cnt[4*t+0], a1 = cnt[4*t+1], a2 = cnt[4*t+2], a3 = cnt[4*t+3];
  part[t] = a0 + a1 + a2 + a3;
  __syncthreads();
  for (int off = 1; off < 1024; off <<= 1) {
    int v = (t >= off) ? part[t - off] : 0;
    __syncthreads();
    part[t] += v;
    __syncthreads();
  }
  int excl = (t == 0) ? 0 : part[t-1];
  int o0 = excl, o1 = o0 + a0, o2 = o1 + a1, o3 = o2 + a2;
  offsets[4*t+0] = o0; offsets[4*t+1] = o1; offsets[4*t+2] = o2; offsets[4*t+3] = o3;
  cursor [4*t+0] = o0; cursor [4*t+1] = o1; cursor [4*t+2] = o2; cursor [4*t+3] = o3;
  if (t == 0) offsets[N] = total;
}

__global__ void scatter_k(const int* __restrict__ dst, int* __restrict__ cursor,
                          int* __restrict__ csr, int E) {
  int e = blockIdx.x * blockDim.x + threadIdx.x;
  if (e < E) {
    int d = dst[e];
    int pos = atomicAdd(&cursor[d], 1);
    csr[pos] = e;
  }
}

// ---------------- edge MLP: z = [relu(ea@W1+b1), 1] ----------------
__global__ void edge_z_k(const float* __restrict__ ea, const float* __restrict__ W1,
                         const float* __restrict__ b1, float* __restrict__ z, int E) {
  int idx = blockIdx.x * blockDim.x + threadIdx.x;
  if (idx >= E * 33) return;
  int e = idx / 33;
  int k = idx - e * 33;
  float v;
  if (k == 32) {
    v = 1.f;  // constant channel carries the b2 term through S
  } else {
    float a0 = ea[e*3+0], a1 = ea[e*3+1], a2 = ea[e*3+2];
    v = fmaxf(a0 * W1[k] + a1 * W1[32 + k] + a2 * W1[64 + k] + b1[k], 0.f);
  }
  z[idx] = v;
}

// ---------------- W2'^T build: [cout][Kpad] bf16 hi/lo; k-rows 0..31 W2, 32 b2, 33 root ----------------
__global__ void build_W2pT_k(const float* __restrict__ W2, const float* __restrict__ b2,
                             const float* __restrict__ root,
                             uint16_t* __restrict__ Bhi, uint16_t* __restrict__ Blo,
                             int cin, int cout, int Kpad) {
  int idx = blockIdx.x * blockDim.x + threadIdx.x;
  int total = cout * Kpad;
  if (idx >= total) return;
  int o  = idx / Kpad;
  int ki = idx - o * Kpad;
  float v = 0.f;
  if (ki < 34 * cin) {
    int k = ki / cin;
    int i = ki - k * cin;
    if (k < 32)       v = W2[(size_t)k * cin * cout + (size_t)i * cout + o];
    else if (k == 32) v = b2[(size_t)i * cout + o];
    else              v = root[(size_t)i * cout + o];
  }
  uint16_t hi, lo;
  split_bf(v, hi, lo);
  Bhi[idx] = hi;
  Blo[idx] = lo;
}

// ---------------- S build (bf16 hi/lo out, stride Kpad) ----------------
// S[n, k*cin+i] = (1/deg) * sum_{e: dst==n} z[e,k]*h[src[e],i]   (k<33)
// rows [33*cin, 34*cin) = h[n,:]; rows [34*cin, Kpad) = 0
template<int CIN>
__global__ __launch_bounds__(256) void build_S_k(const float* __restrict__ h,
                                                 const float* __restrict__ z,
                                                 const int* __restrict__ src,
                                                 const int* __restrict__ csr,
                                                 const int* __restrict__ offsets,
                                                 uint16_t* __restrict__ Shi,
                                                 uint16_t* __restrict__ Slo,
                                                 int Kpad) {
  constexpr int CH = 8;
  constexpr int K1 = 33 * CIN;
  constexpr int KT = 34 * CIN;
  constexpr int NACC = (K1 + 255) / 256;
  __shared__ float hs[CH][CIN];
  __shared__ float zs[CH][33];
  __shared__ int   es[CH];
  const int n = blockIdx.x;
  const int tid = threadIdx.x;
  const int base = offsets[n];
  const int deg  = offsets[n+1] - base;
  const float scale = 1.f / fmaxf((float)deg, 1.f);
  float acc[NACC];
#pragma unroll
  for (int q = 0; q < NACC; q++) acc[q] = 0.f;

  for (int c0 = 0; c0 < deg; c0 += CH) {
    const int cc = min(CH, deg - c0);
    if (tid < cc) es[tid] = csr[base + c0 + tid];
    __syncthreads();
    for (int idx = tid; idx < cc * CIN; idx += 256) {
      int e_slot = idx / CIN, i = idx - e_slot * CIN;
      hs[e_slot][i] = h[(size_t)src[es[e_slot]] * CIN + i];
    }
    for (int idx = tid; idx < cc * 33; idx += 256) {
      int e_slot = idx / 33, k = idx - e_slot * 33;
      zs[e_slot][k] = z[(size_t)es[e_slot] * 33 + k];
    }
    __syncthreads();
#pragma unroll
    for (int q = 0; q < NACC; q++) {
      int ki = tid + q * 256;
      if (ki < K1) {
        int k = ki / CIN, i = ki - (ki / CIN) * CIN;
        float a = acc[q];
        for (int c = 0; c < cc; c++) a += zs[c][k] * hs[c][i];
        acc[q] = a;
      }
    }
    __syncthreads();
  }
  const size_t rowb = (size_t)n * Kpad;
#pragma unroll
  for (int q = 0; q < NACC; q++) {
    int ki = tid + q * 256;
    if (ki < K1) {
      uint16_t hi, lo;
      split_bf(acc[q] * scale, hi, lo);
      Shi[rowb + ki] = hi;
      Slo[rowb + ki] = lo;
    }
  }
  for (int i = tid; i < CIN; i += 256) {
    uint16_t hi, lo;
    split_bf(h[(size_t)n * CIN + i], hi, lo);
    Shi[rowb + K1 + i] = hi;
    Slo[rowb + K1 + i] = lo;
  }
  for (int ki = KT + tid; ki < Kpad; ki += 256) {
    Shi[rowb + ki] = 0;
    Slo[rowb + ki] = 0;
  }
}

// ---------------- MFMA bf16x3 GEMM with fused bias+BN+ReLU ----------------
// C[m, n] = relu(bn(A[m,:]@B[n,:]^T + bias[n])), A: [4096][Kpad] hi/lo, B: [Ncol][Kpad] hi/lo
__global__ __launch_bounds__(256) void mfma_gemm_k(const uint16_t* __restrict__ Ahi,
                                                   const uint16_t* __restrict__ Alo,
                                                   const uint16_t* __restrict__ Bhi,
                                                   const uint16_t* __restrict__ Blo,
                                                   const float* __restrict__ bias,
                                                   const float* __restrict__ bg,
                                                   const float* __restrict__ bb,
                                                   const float* __restrict__ bnm,
                                                   const float* __restrict__ bnv,
                                                   float* __restrict__ C,
                                                   int Kpad, int Ncol) {
  __shared__ uint16_t As[2][64][72];  // [hi/lo][row][k], +8 pad breaks bank aliasing
  __shared__ uint16_t Bs[2][64][72];
  const int m0 = blockIdx.x * 64, n0 = blockIdx.y * 64;
  const int tid  = threadIdx.x;
  const int lane = tid & 63;
  const int wave = tid >> 6;       // 4 waves
  const int wm = wave & 1, wn = wave >> 1;   // 32x32 quadrant per wave
  const int q  = lane >> 4;        // 0..3
  const int mr = lane & 15;

  // per-lane output columns and fused BN coefficients
  const int col0 = n0 + wn * 32 + mr;
  float s[2], t[2];
#pragma unroll
  for (int fn = 0; fn < 2; fn++) {
    int c = col0 + fn * 16;
    float sc = bg[c] * rsqrtf(bnv[c] + BN_EPS);
    s[fn] = sc;
    t[fn] = (bias[c] - bnm[c]) * sc + bb[c];
  }

  f32x4 acc[2][2];
#pragma unroll
  for (int a = 0; a < 2; a++)
#pragma unroll
    for (int b = 0; b < 2; b++) acc[a][b] = (f32x4)0.f;

  for (int k0 = 0; k0 < Kpad; k0 += 64) {
#pragma unroll
    for (int rep = 0; rep < 2; rep++) {
      int chunk = rep * 256 + tid;
      int r = chunk >> 3, c = chunk & 7;  // 8 threads per row -> coalesced 16B
      size_t ga = (size_t)(m0 + r) * Kpad + k0 + c * 8;
      size_t gb = (size_t)(n0 + r) * Kpad + k0 + c * 8;
      *(uint4*)&As[0][r][c * 8] = *(const uint4*)(Ahi + ga);
      *(uint4*)&As[1][r][c * 8] = *(const uint4*)(Alo + ga);
      *(uint4*)&Bs[0][r][c * 8] = *(const uint4*)(Bhi + gb);
      *(uint4*)&Bs[1][r][c * 8] = *(const uint4*)(Blo + gb);
    }
    __syncthreads();
#pragma unroll
    for (int ks = 0; ks < 2; ks++) {
      const int kb = ks * 32 + q * 8;
      bf16x8 ah[2], al[2], bh[2], bl[2];
#pragma unroll
      for (int f = 0; f < 2; f++) {
        ah[f] = *(const bf16x8*)&As[0][wm * 32 + f * 16 + mr][kb];
        al[f] = *(const bf16x8*)&As[1][wm * 32 + f * 16 + mr][kb];
        bh[f] = *(const bf16x8*)&Bs[0][wn * 32 + f * 16 + mr][kb];
        bl[f] = *(const bf16x8*)&Bs[1][wn * 32 + f * 16 + mr][kb];
      }
#pragma unroll
      for (int fm = 0; fm < 2; fm++)
#pragma unroll
        for (int fn = 0; fn < 2; fn++) {
          acc[fm][fn] = __builtin_amdgcn_mfma_f32_16x16x32_bf16(ah[fm], bh[fn], acc[fm][fn], 0, 0, 0);
          acc[fm][fn] = __builtin_amdgcn_mfma_f32_16x16x32_bf16(ah[fm], bl[fn], acc[fm][fn], 0, 0, 0);
          acc[fm][fn] = __builtin_amdgcn_mfma_f32_16x16x32_bf16(al[fm], bh[fn], acc[fm][fn], 0, 0, 0);
        }
    }
    __syncthreads();
  }

  // epilogue: D row = quad*4 + reg, col = lane&15 (measured m89/m91 C/D layout)
#pragma unroll
  for (int fm = 0; fm < 2; fm++) {
#pragma unroll
    for (int reg = 0; reg < 4; reg++) {
      int row = m0 + wm * 32 + fm * 16 + q * 4 + reg;
#pragma unroll
      for (int fn = 0; fn < 2; fn++) {
        int col = col0 + fn * 16;
        float val = acc[fm][fn][reg] * s[fn] + t[fn];
        C[(size_t)row * Ncol + col] = fmaxf(val, 0.f);
      }
    }
  }
}

// ---------------- pooling ----------------
__global__ void pool_k(const float* __restrict__ h, const int* __restrict__ seg,
                       float* __restrict__ psum, float* __restrict__ pcnt) {
  int n = blockIdx.x, o = threadIdx.x;  // 256 threads
  int g = seg[n];
  atomicAdd(&psum[(size_t)g * 256 + o], h[(size_t)n * 256 + o]);
  if (o == 0) atomicAdd(&pcnt[g], 1.f);
}

__global__ __launch_bounds__(128) void final_k(const float* __restrict__ psum,
                                               const float* __restrict__ pcnt,
                                               const float* __restrict__ W,
                                               const float* __restrict__ b,
                                               float* __restrict__ out, int T) {
  __shared__ float pooled[256];
  int g = blockIdx.x, t = threadIdx.x;
  float ic = 1.f / fmaxf(pcnt[g], 1.f);
  for (int o = t; o < 256; o += 128) pooled[o] = psum[(size_t)g * 256 + o] * ic;
  __syncthreads();
  if (t < T) {
    float s = b[t];
    for (int o = 0; o < 256; o++) s += pooled[o] * W[(size_t)o * T + t];
    out[(size_t)g * T + t] = (s > 0.f) ? s : 0.1f * s;
  }
}

// ---------------- host orchestration ----------------
extern "C" void kernel_launch(void* const* d_in, const int* in_sizes, int n_in,
                              void* d_out, int out_size, void* d_ws, size_t ws_size,
                              hipStream_t stream) {
  const float* x   = (const float*)d_in[0];
  const int*   ei  = (const int*)d_in[1];
  const float* ea  = (const float*)d_in[2];
  const int*   seg = (const int*)d_in[3];

  const int N = in_sizes[0] / 5;       // 4096
  const int E = in_sizes[2] / 3;       // 16384
  const int T = in_sizes[35];          // 100
  const int G = out_size / T;          // 128
  const int* src = ei;
  const int* dst = ei + E;

  const float *W1[3], *b1[3], *W2[3], *b2[3], *root[3], *bias[3];
  const float *bng[3], *bnb[3], *bnm[3], *bnv[3];
  for (int l = 0; l < 3; l++) {
    int base = 4 + l * 10;
    W1[l]   = (const float*)d_in[base + 0];
    b1[l]   = (const float*)d_in[base + 1];
    W2[l]   = (const float*)d_in[base + 2];
    b2[l]   = (const float*)d_in[base + 3];
    root[l] = (const float*)d_in[base + 4];
    bias[l] = (const float*)d_in[base + 5];
    bng[l]  = (const float*)d_in[base + 6];
    bnb[l]  = (const float*)d_in[base + 7];
    bnm[l]  = (const float*)d_in[base + 8];
    bnv[l]  = (const float*)d_in[base + 9];
  }
  const float* mlpW = (const float*)d_in[34];
  const float* mlpb = (const float*)d_in[35];

  // workspace carve (256B aligned chunks)
  char* p = (char*)d_ws;
  auto carve = [&](size_t bytes) -> char* {
    char* r = p;
    p += (bytes + 255) & ~(size_t)255;
    return r;
  };
  const int KPADMAX = 4352;
  int*      cnt     = (int*)carve((size_t)N * 4);
  int*      offsets = (int*)carve((size_t)(N + 1) * 4);
  int*      cursor  = (int*)carve((size_t)N * 4);
  int*      csr     = (int*)carve((size_t)E * 4);
  float*    z       = (float*)carve((size_t)E * 33 * 4);
  uint16_t* Whi     = (uint16_t*)carve((size_t)256 * KPADMAX * 2);
  uint16_t* Wlo     = (uint16_t*)carve((size_t)256 * KPADMAX * 2);
  uint16_t* Shi     = (uint16_t*)carve((size_t)N * KPADMAX * 2);
  uint16_t* Slo     = (uint16_t*)carve((size_t)N * KPADMAX * 2);
  float*    hA      = (float*)carve((size_t)N * 256 * 4);
  float*    hB      = (float*)carve((size_t)N * 256 * 4);
  float*    psum    = (float*)carve((size_t)G * 256 * 4);
  float*    pcnt    = (float*)carve((size_t)G * 4);

  // CSR over dst
  zero_i32_k<<<(N + 255) / 256, 256, 0, stream>>>(cnt, N);
  hist_k<<<(E + 255) / 256, 256, 0, stream>>>(dst, cnt, E);
  scan_k<<<1, 1024, 0, stream>>>(cnt, offsets, cursor, N, E);
  scatter_k<<<(E + 255) / 256, 256, 0, stream>>>(dst, cursor, csr, E);

  const int cins[3]  = {5, 64, 128};
  const int couts[3] = {64, 128, 256};
  const int kpads[3] = {192, 2176, 4352};
  const float* hin = x;
  float* houts[3] = {hA, hB, hA};

  for (int l = 0; l < 3; l++) {
    int cin = cins[l], cout = couts[l], Kpad = kpads[l];
    edge_z_k<<<(E * 33 + 255) / 256, 256, 0, stream>>>(ea, W1[l], b1[l], z, E);
    build_W2pT_k<<<(cout * Kpad + 255) / 256, 256, 0, stream>>>(W2[l], b2[l], root[l],
                                                                Whi, Wlo, cin, cout, Kpad);
    if (cin == 5)
      build_S_k<5><<<N, 256, 0, stream>>>(hin, z, src, csr, offsets, Shi, Slo, Kpad);
    else if (cin == 64)
      build_S_k<64><<<N, 256, 0, stream>>>(hin, z, src, csr, offsets, Shi, Slo, Kpad);
    else
      build_S_k<128><<<N, 256, 0, stream>>>(hin, z, src, csr, offsets, Shi, Slo, Kpad);
    dim3 grid(N / 64, cout / 64);
    mfma_gemm_k<<<grid, 256, 0, stream>>>(Shi, Slo, Whi, Wlo, bias[l], bng[l], bnb[l],
                                          bnm[l], bnv[l], houts[l], Kpad, cout);
    hin = houts[l];
  }

  zero_f32_k<<<(G * 256 + 255) / 256, 256, 0, stream>>>(psum, G * 256);
  zero_f32_k<<<(G + 255) / 256, 256, 0, stream>>>(pcnt, G);
  pool_k<<<N, 256, 0, stream>>>(hA, seg, psum, pcnt);
  final_k<<<G, 128, 0, stream>>>(psum, pcnt, mlpW, mlpb, (float*)d_out, T);
}

// Round 3
// 289.961 us; speedup vs baseline: 4.1761x; 1.2512x over previous
//
#include <hip/hip_runtime.h>
#include <cstdint>
#include <cstddef>

#define BN_EPS 1e-5f

typedef short bf16x8 __attribute__((ext_vector_type(8)));
typedef float f32x4  __attribute__((ext_vector_type(4)));
typedef unsigned short u16x8 __attribute__((ext_vector_type(8)));

__device__ __forceinline__ uint16_t f2bf_rte(float f) {
  uint32_t u = __float_as_uint(f);
  uint32_t r = u + 0x7fffu + ((u >> 16) & 1u);
  return (uint16_t)(r >> 16);
}
__device__ __forceinline__ float bf2f(uint16_t h) {
  return __uint_as_float(((uint32_t)h) << 16);
}
__device__ __forceinline__ void split_bf(float v, uint16_t& hi, uint16_t& lo) {
  hi = f2bf_rte(v);
  lo = f2bf_rte(v - bf2f(hi));
}

// ---------------- CSR build over dst ----------------
__global__ void zero_i32_k(int* p, int n) {
  int i = blockIdx.x * blockDim.x + threadIdx.x;
  if (i < n) p[i] = 0;
}

__global__ void hist_k(const int* __restrict__ dst, int* __restrict__ cnt, int E) {
  int e = blockIdx.x * blockDim.x + threadIdx.x;
  if (e < E) atomicAdd(&cnt[dst[e]], 1);
}

__global__ __launch_bounds__(1024) void scan_k(const int* __restrict__ cnt,
                                               int* __restrict__ offsets,
                                               int* __restrict__ cursor,
                                               int N, int total) {
  __shared__ int part[1024];
  int t = threadIdx.x;
  int a0 = cnt[4*t+0], a1 = cnt[4*t+1], a2 = cnt[4*t+2], a3 = cnt[4*t+3];
  part[t] = a0 + a1 + a2 + a3;
  __syncthreads();
  for (int off = 1; off < 1024; off <<= 1) {
    int v = (t >= off) ? part[t - off] : 0;
    __syncthreads();
    part[t] += v;
    __syncthreads();
  }
  int excl = (t == 0) ? 0 : part[t-1];
  int o0 = excl, o1 = o0 + a0, o2 = o1 + a1, o3 = o2 + a2;
  offsets[4*t+0] = o0; offsets[4*t+1] = o1; offsets[4*t+2] = o2; offsets[4*t+3] = o3;
  cursor [4*t+0] = o0; cursor [4*t+1] = o1; cursor [4*t+2] = o2; cursor [4*t+3] = o3;
  if (t == 0) offsets[N] = total;
}

__global__ void scatter_k(const int* __restrict__ dst, int* __restrict__ cursor,
                          int* __restrict__ csr, int E) {
  int e = blockIdx.x * blockDim.x + threadIdx.x;
  if (e < E) {
    int d = dst[e];
    int pos = atomicAdd(&cursor[d], 1);
    csr[pos] = e;
  }
}

// ---------------- W2'^T build: [cout][Kpad] bf16 hi/lo; k 0..31 W2, 32 b2, 33 root ----------------
__global__ void build_W2pT_k(const float* __restrict__ W2, const float* __restrict__ b2,
                             const float* __restrict__ root,
                             uint16_t* __restrict__ Bhi, uint16_t* __restrict__ Blo,
                             int cin, int cout, int Kpad) {
  int idx = blockIdx.x * blockDim.x + threadIdx.x;
  int total = cout * Kpad;
  if (idx >= total) return;
  int o  = idx / Kpad;
  int ki = idx - o * Kpad;
  float v = 0.f;
  if (ki < 34 * cin) {
    int k = ki / cin;
    int i = ki - k * cin;
    if (k < 32)       v = W2[(size_t)k * cin * cout + (size_t)i * cout + o];
    else if (k == 32) v = b2[(size_t)i * cout + o];
    else              v = root[(size_t)i * cout + o];
  }
  uint16_t hi, lo;
  split_bf(v, hi, lo);
  Bhi[idx] = hi;
  Blo[idx] = lo;
}

// ---------------- S build, vectorized (CIN in {64,128}), fused edge-MLP z ----------------
// S[n, k*cin+i] = (1/deg) * sum_{e: dst==n} z[e,k]*h[src[e],i]   (k<33, z[.,32]=1)
// rows [33*cin, 34*cin) = h[n,:]
template<int CIN>
__global__ __launch_bounds__(256) void build_S_vec_k(const float* __restrict__ h,
                                                     const float* __restrict__ ea,
                                                     const float* __restrict__ W1,
                                                     const float* __restrict__ b1,
                                                     const int* __restrict__ src,
                                                     const int* __restrict__ csr,
                                                     const int* __restrict__ offsets,
                                                     uint16_t* __restrict__ Shi,
                                                     uint16_t* __restrict__ Slo,
                                                     int Kpad) {
  constexpr int CH = 8;
  constexpr int K1 = 33 * CIN;
  constexpr int NCH = K1 / 8;          // 16B chunks (CIN multiple of 8)
  constexpr int NP = (NCH + 255) / 256;
  __shared__ float hs[CH][CIN];
  __shared__ float zs[CH][33];
  __shared__ int   es[CH];
  const int n = blockIdx.x;
  const int tid = threadIdx.x;
  const int base = offsets[n];
  const int deg  = offsets[n+1] - base;
  const float scale = 1.f / fmaxf((float)deg, 1.f);
  float acc[NP][8];
#pragma unroll
  for (int p = 0; p < NP; p++)
#pragma unroll
    for (int j = 0; j < 8; j++) acc[p][j] = 0.f;

  for (int c0 = 0; c0 < deg; c0 += CH) {
    const int cc = min(CH, deg - c0);
    if (tid < cc) es[tid] = csr[base + c0 + tid];
    __syncthreads();
    for (int idx = tid; idx < cc * CIN; idx += 256) {
      int slot = idx / CIN, i = idx - slot * CIN;
      hs[slot][i] = h[(size_t)src[es[slot]] * CIN + i];
    }
    for (int idx = tid; idx < cc * 33; idx += 256) {
      int slot = idx / 33, k = idx - slot * 33;
      float v;
      if (k == 32) v = 1.f;
      else {
        int e = es[slot];
        v = fmaxf(ea[e*3+0] * W1[k] + ea[e*3+1] * W1[32 + k] + ea[e*3+2] * W1[64 + k] + b1[k], 0.f);
      }
      zs[slot][k] = v;
    }
    __syncthreads();
#pragma unroll
    for (int p = 0; p < NP; p++) {
      int ch = p * 256 + tid;
      if (ch < NCH) {
        int ki0 = ch * 8;
        int k  = ki0 / CIN;
        int i0 = ki0 & (CIN - 1);
        for (int c = 0; c < cc; c++) {
          float zv = zs[c][k];
          float4 h0 = *(const float4*)&hs[c][i0];
          float4 h1 = *(const float4*)&hs[c][i0 + 4];
          acc[p][0] += zv * h0.x; acc[p][1] += zv * h0.y;
          acc[p][2] += zv * h0.z; acc[p][3] += zv * h0.w;
          acc[p][4] += zv * h1.x; acc[p][5] += zv * h1.y;
          acc[p][6] += zv * h1.z; acc[p][7] += zv * h1.w;
        }
      }
    }
    __syncthreads();
  }
  const size_t rowb = (size_t)n * Kpad;
#pragma unroll
  for (int p = 0; p < NP; p++) {
    int ch = p * 256 + tid;
    if (ch < NCH) {
      u16x8 hv, lv;
#pragma unroll
      for (int j = 0; j < 8; j++) {
        uint16_t hi, lo;
        split_bf(acc[p][j] * scale, hi, lo);
        hv[j] = hi; lv[j] = lo;
      }
      *(u16x8*)(Shi + rowb + ch * 8) = hv;
      *(u16x8*)(Slo + rowb + ch * 8) = lv;
    }
  }
  // root rows = h[n,:]
  for (int c = tid; c < CIN / 8; c += 256) {
    int i0 = c * 8;
    float4 a = *(const float4*)&h[(size_t)n * CIN + i0];
    float4 b = *(const float4*)&h[(size_t)n * CIN + i0 + 4];
    float vals[8] = {a.x, a.y, a.z, a.w, b.x, b.y, b.z, b.w};
    u16x8 hv, lv;
#pragma unroll
    for (int j = 0; j < 8; j++) {
      uint16_t hi, lo;
      split_bf(vals[j], hi, lo);
      hv[j] = hi; lv[j] = lo;
    }
    *(u16x8*)(Shi + rowb + K1 + i0) = hv;
    *(u16x8*)(Slo + rowb + K1 + i0) = lv;
  }
  // pad region (none when 34*CIN == Kpad)
  for (int ki = 34 * CIN + tid; ki < Kpad; ki += 256) {
    Shi[rowb + ki] = 0;
    Slo[rowb + ki] = 0;
  }
}

// scalar variant for CIN=5 (layer 1; tiny)
__global__ __launch_bounds__(256) void build_S5_k(const float* __restrict__ h,
                                                  const float* __restrict__ ea,
                                                  const float* __restrict__ W1,
                                                  const float* __restrict__ b1,
                                                  const int* __restrict__ src,
                                                  const int* __restrict__ csr,
                                                  const int* __restrict__ offsets,
                                                  uint16_t* __restrict__ Shi,
                                                  uint16_t* __restrict__ Slo,
                                                  int Kpad) {
  constexpr int CIN = 5, CH = 8;
  constexpr int K1 = 33 * CIN;   // 165
  constexpr int KT = 34 * CIN;   // 170
  __shared__ float hs[CH][CIN];
  __shared__ float zs[CH][33];
  __shared__ int   es[CH];
  const int n = blockIdx.x;
  const int tid = threadIdx.x;
  const int base = offsets[n];
  const int deg  = offsets[n+1] - base;
  const float scale = 1.f / fmaxf((float)deg, 1.f);
  float acc = 0.f;

  for (int c0 = 0; c0 < deg; c0 += CH) {
    const int cc = min(CH, deg - c0);
    if (tid < cc) es[tid] = csr[base + c0 + tid];
    __syncthreads();
    for (int idx = tid; idx < cc * CIN; idx += 256) {
      int slot = idx / CIN, i = idx - slot * CIN;
      hs[slot][i] = h[(size_t)src[es[slot]] * CIN + i];
    }
    for (int idx = tid; idx < cc * 33; idx += 256) {
      int slot = idx / 33, k = idx - slot * 33;
      float v;
      if (k == 32) v = 1.f;
      else {
        int e = es[slot];
        v = fmaxf(ea[e*3+0] * W1[k] + ea[e*3+1] * W1[32 + k] + ea[e*3+2] * W1[64 + k] + b1[k], 0.f);
      }
      zs[slot][k] = v;
    }
    __syncthreads();
    if (tid < K1) {
      int k = tid / CIN, i = tid - (tid / CIN) * CIN;
      float a = acc;
      for (int c = 0; c < cc; c++) a += zs[c][k] * hs[c][i];
      acc = a;
    }
    __syncthreads();
  }
  const size_t rowb = (size_t)n * Kpad;
  if (tid < K1) {
    uint16_t hi, lo;
    split_bf(acc * scale, hi, lo);
    Shi[rowb + tid] = hi;
    Slo[rowb + tid] = lo;
  }
  if (tid < CIN) {
    uint16_t hi, lo;
    split_bf(h[(size_t)n * CIN + tid], hi, lo);
    Shi[rowb + K1 + tid] = hi;
    Slo[rowb + K1 + tid] = lo;
  }
  for (int ki = KT + tid; ki < Kpad; ki += 256) {
    Shi[rowb + ki] = 0;
    Slo[rowb + ki] = 0;
  }
}

// ---------------- split-K MFMA bf16x3 GEMM: writes fp32 partials ----------------
// Cpart[z][m][n] = A[m, krange_z] @ B[n, krange_z]^T
__global__ __launch_bounds__(256, 4) void mfma_gemm_sk_k(const uint16_t* __restrict__ Ahi,
                                                         const uint16_t* __restrict__ Alo,
                                                         const uint16_t* __restrict__ Bhi,
                                                         const uint16_t* __restrict__ Blo,
                                                         float* __restrict__ Cpart,
                                                         int Kpad, int Ncol, int M,
                                                         int itersPerSplit) {
  __shared__ uint16_t As[2][64][72];  // [hi/lo][row][k], +8 pad breaks bank aliasing
  __shared__ uint16_t Bs[2][64][72];
  const int m0 = blockIdx.x * 64, n0 = blockIdx.y * 64;
  const int kbeg = blockIdx.z * itersPerSplit * 64;
  const int kend = min(Kpad, kbeg + itersPerSplit * 64);
  const int tid  = threadIdx.x;
  const int lane = tid & 63;
  const int wave = tid >> 6;
  const int wm = wave & 1, wn = wave >> 1;
  const int q  = lane >> 4;
  const int mr = lane & 15;

  f32x4 acc[2][2];
#pragma unroll
  for (int a = 0; a < 2; a++)
#pragma unroll
    for (int b = 0; b < 2; b++) acc[a][b] = (f32x4)0.f;

  for (int k0 = kbeg; k0 < kend; k0 += 64) {
#pragma unroll
    for (int rep = 0; rep < 2; rep++) {
      int chunk = rep * 256 + tid;
      int r = chunk >> 3, c = chunk & 7;
      size_t ga = (size_t)(m0 + r) * Kpad + k0 + c * 8;
      size_t gb = (size_t)(n0 + r) * Kpad + k0 + c * 8;
      *(uint4*)&As[0][r][c * 8] = *(const uint4*)(Ahi + ga);
      *(uint4*)&As[1][r][c * 8] = *(const uint4*)(Alo + ga);
      *(uint4*)&Bs[0][r][c * 8] = *(const uint4*)(Bhi + gb);
      *(uint4*)&Bs[1][r][c * 8] = *(const uint4*)(Blo + gb);
    }
    __syncthreads();
#pragma unroll
    for (int ks = 0; ks < 2; ks++) {
      const int kb = ks * 32 + q * 8;
      bf16x8 ah[2], al[2], bh[2], bl[2];
#pragma unroll
      for (int f = 0; f < 2; f++) {
        ah[f] = *(const bf16x8*)&As[0][wm * 32 + f * 16 + mr][kb];
        al[f] = *(const bf16x8*)&As[1][wm * 32 + f * 16 + mr][kb];
        bh[f] = *(const bf16x8*)&Bs[0][wn * 32 + f * 16 + mr][kb];
        bl[f] = *(const bf16x8*)&Bs[1][wn * 32 + f * 16 + mr][kb];
      }
#pragma unroll
      for (int fm = 0; fm < 2; fm++)
#pragma unroll
        for (int fn = 0; fn < 2; fn++) {
          acc[fm][fn] = __builtin_amdgcn_mfma_f32_16x16x32_bf16(ah[fm], bh[fn], acc[fm][fn], 0, 0, 0);
          acc[fm][fn] = __builtin_amdgcn_mfma_f32_16x16x32_bf16(ah[fm], bl[fn], acc[fm][fn], 0, 0, 0);
          acc[fm][fn] = __builtin_amdgcn_mfma_f32_16x16x32_bf16(al[fm], bh[fn], acc[fm][fn], 0, 0, 0);
        }
    }
    __syncthreads();
  }

  // D row = quad*4 + reg, col = lane&15 (verified layout)
  float* Cz = Cpart + (size_t)blockIdx.z * M * Ncol;
#pragma unroll
  for (int fm = 0; fm < 2; fm++) {
#pragma unroll
    for (int reg = 0; reg < 4; reg++) {
      int row = m0 + wm * 32 + fm * 16 + q * 4 + reg;
#pragma unroll
      for (int fn = 0; fn < 2; fn++) {
        int col = n0 + wn * 32 + fn * 16 + mr;
        Cz[(size_t)row * Ncol + col] = acc[fm][fn][reg];
      }
    }
  }
}

// ---------------- split-K reduce + bias + BN + ReLU epilogue ----------------
__global__ void epilogue_k(const float* __restrict__ Cpart, int SK, size_t plane4,
                           int Ncol,
                           const float* __restrict__ bias, const float* __restrict__ bg,
                           const float* __restrict__ bb, const float* __restrict__ bnm,
                           const float* __restrict__ bnv,
                           float* __restrict__ C, int total4) {
  int i = blockIdx.x * blockDim.x + threadIdx.x;
  if (i >= total4) return;
  float4 v = {0.f, 0.f, 0.f, 0.f};
  for (int z = 0; z < SK; z++) {
    float4 p = *((const float4*)Cpart + (size_t)z * plane4 + i);
    v.x += p.x; v.y += p.y; v.z += p.z; v.w += p.w;
  }
  int col0 = (i * 4) % Ncol;
  float o[4] = {v.x, v.y, v.z, v.w};
#pragma unroll
  for (int j = 0; j < 4; j++) {
    int c = col0 + j;
    float s = bg[c] * rsqrtf(bnv[c] + BN_EPS);
    float val = (o[j] + bias[c] - bnm[c]) * s + bb[c];
    o[j] = fmaxf(val, 0.f);
  }
  float4 r = {o[0], o[1], o[2], o[3]};
  *((float4*)C + i) = r;
}

// ---------------- fused pool (mean over sorted batch_seg) + final MLP + LeakyReLU ----------------
__global__ __launch_bounds__(256) void pool_final_k(const float* __restrict__ h,
                                                    const int* __restrict__ seg,
                                                    const float* __restrict__ W,
                                                    const float* __restrict__ b,
                                                    float* __restrict__ out,
                                                    int N, int T) {
  __shared__ float pooled[256];
  const int g = blockIdx.x, tid = threadIdx.x;
  // lower_bound(seg, g) and lower_bound(seg, g+1); seg is sorted
  int lo = 0, hi = N;
  while (lo < hi) { int mid = (lo + hi) >> 1; if (seg[mid] < g) lo = mid + 1; else hi = mid; }
  int lo2 = lo, hi2 = N;
  while (lo2 < hi2) { int mid = (lo2 + hi2) >> 1; if (seg[mid] < g + 1) lo2 = mid + 1; else hi2 = mid; }
  const int cnt = lo2 - lo;
  const float inv = 1.f / fmaxf((float)cnt, 1.f);
  float s = 0.f;
  for (int n = lo; n < lo2; n++) s += h[(size_t)n * 256 + tid];
  pooled[tid] = s * inv;
  __syncthreads();
  if (tid < T) {
    float acc = b[tid];
    for (int o = 0; o < 256; o++) acc += pooled[o] * W[(size_t)o * T + tid];
    out[(size_t)g * T + tid] = (acc > 0.f) ? acc : 0.1f * acc;
  }
}

// ---------------- host orchestration ----------------
extern "C" void kernel_launch(void* const* d_in, const int* in_sizes, int n_in,
                              void* d_out, int out_size, void* d_ws, size_t ws_size,
                              hipStream_t stream) {
  const float* x   = (const float*)d_in[0];
  const int*   ei  = (const int*)d_in[1];
  const float* ea  = (const float*)d_in[2];
  const int*   seg = (const int*)d_in[3];

  const int N = in_sizes[0] / 5;       // 4096
  const int E = in_sizes[2] / 3;       // 16384
  const int T = in_sizes[35];          // 100
  const int G = out_size / T;          // 128
  const int* src = ei;
  const int* dst = ei + E;

  const float *W1[3], *b1[3], *W2[3], *b2[3], *root[3], *bias[3];
  const float *bng[3], *bnb[3], *bnm[3], *bnv[3];
  for (int l = 0; l < 3; l++) {
    int base = 4 + l * 10;
    W1[l]   = (const float*)d_in[base + 0];
    b1[l]   = (const float*)d_in[base + 1];
    W2[l]   = (const float*)d_in[base + 2];
    b2[l]   = (const float*)d_in[base + 3];
    root[l] = (const float*)d_in[base + 4];
    bias[l] = (const float*)d_in[base + 5];
    bng[l]  = (const float*)d_in[base + 6];
    bnb[l]  = (const float*)d_in[base + 7];
    bnm[l]  = (const float*)d_in[base + 8];
    bnv[l]  = (const float*)d_in[base + 9];
  }
  const float* mlpW = (const float*)d_in[34];
  const float* mlpb = (const float*)d_in[35];

  char* p = (char*)d_ws;
  auto carve = [&](size_t bytes) -> char* {
    char* r = p;
    p += (bytes + 255) & ~(size_t)255;
    return r;
  };
  const int KPADMAX = 4352;
  const int SKMAX = 8;
  int*      cnt     = (int*)carve((size_t)N * 4);
  int*      offsets = (int*)carve((size_t)(N + 1) * 4);
  int*      cursor  = (int*)carve((size_t)N * 4);
  int*      csr     = (int*)carve((size_t)E * 4);
  uint16_t* Whi     = (uint16_t*)carve((size_t)256 * KPADMAX * 2);
  uint16_t* Wlo     = (uint16_t*)carve((size_t)256 * KPADMAX * 2);
  uint16_t* Shi     = (uint16_t*)carve((size_t)N * KPADMAX * 2);
  uint16_t* Slo     = (uint16_t*)carve((size_t)N * KPADMAX * 2);
  float*    Cpart   = (float*)carve((size_t)SKMAX * N * 256 * 4 / 2);  // 8*4096*128 or 4*4096*256
  float*    hA      = (float*)carve((size_t)N * 256 * 4);
  float*    hB      = (float*)carve((size_t)N * 128 * 4);

  // CSR over dst
  zero_i32_k<<<(N + 255) / 256, 256, 0, stream>>>(cnt, N);
  hist_k<<<(E + 255) / 256, 256, 0, stream>>>(dst, cnt, E);
  scan_k<<<1, 1024, 0, stream>>>(cnt, offsets, cursor, N, E);
  scatter_k<<<(E + 255) / 256, 256, 0, stream>>>(dst, cursor, csr, E);

  const int cins[3]  = {5, 64, 128};
  const int couts[3] = {64, 128, 256};
  const int kpads[3] = {192, 2176, 4352};
  const int sks[3]   = {1, 8, 4};
  const float* hin = x;
  float* houts[3] = {hB, hB, hA};
  // layer1 out (64 cols) -> reuse hB? no: layer2 input is layer1 out. Use hA for l1, hB for l2, hA for l3.
  houts[0] = hA; houts[1] = hB; houts[2] = hA;

  for (int l = 0; l < 3; l++) {
    int cin = cins[l], cout = couts[l], Kpad = kpads[l], SK = sks[l];
    int iters = Kpad / 64;
    int ips = (iters + SK - 1) / SK;
    build_W2pT_k<<<(cout * Kpad + 255) / 256, 256, 0, stream>>>(W2[l], b2[l], root[l],
                                                                Whi, Wlo, cin, cout, Kpad);
    if (cin == 5)
      build_S5_k<<<N, 256, 0, stream>>>(hin, ea, W1[l], b1[l], src, csr, offsets, Shi, Slo, Kpad);
    else if (cin == 64)
      build_S_vec_k<64><<<N, 256, 0, stream>>>(hin, ea, W1[l], b1[l], src, csr, offsets, Shi, Slo, Kpad);
    else
      build_S_vec_k<128><<<N, 256, 0, stream>>>(hin, ea, W1[l], b1[l], src, csr, offsets, Shi, Slo, Kpad);
    dim3 grid(N / 64, cout / 64, SK);
    mfma_gemm_sk_k<<<grid, 256, 0, stream>>>(Shi, Slo, Whi, Wlo, Cpart, Kpad, cout, N, ips);
    int total4 = N * cout / 4;
    epilogue_k<<<(total4 + 255) / 256, 256, 0, stream>>>(Cpart, SK, (size_t)N * cout / 4, cout,
                                                         bias[l], bng[l], bnb[l], bnm[l], bnv[l],
                                                         houts[l], total4);
    hin = houts[l];
  }

  pool_final_k<<<G, 256, 0, stream>>>(hA, seg, mlpW, mlpb, (float*)d_out, N, T);
}